// Round 5
// baseline (274.785 us; speedup 1.0000x reference)
//
#include <hip/hip_runtime.h>
#include <stdint.h>

typedef int i32x4  __attribute__((ext_vector_type(4)));
typedef int i32x16 __attribute__((ext_vector_type(16)));

#define HW     56
#define NPIX   3136            // 56*56
#define PADW   58
#define PPIX   3364            // 58*58
#define NB     32
#define CIN    256
#define COUT   256
#define STRW   32              // bytes per (pixel, g) i8 slice
#define ROWB   (PADW*STRW)     // 1856
#define GSTR   (PPIX*STRW)     // 107648 per (n,g) plane
#define NSTR   (8*GSTR)        // 861184 per n
#define NKID   72              // 8 ci-groups * 9 taps
#define NPH    36              // K-phases (2 kidx per phase)

// ---------------------------------------------------------------------------
// Pack sign(x) to i8 (+1/-1), layout xsp[n][g][hh][ww][32], zero border ring
// (conv padding exact). Covers all padded pixels => no memset needed.
// ---------------------------------------------------------------------------
__global__ __launch_bounds__(256) void pack_x(const float* __restrict__ x,
                                              char* __restrict__ xsp) {
    int pp = blockIdx.x * 256 + threadIdx.x;
    if (pp >= PPIX) return;
    int n = blockIdx.y, g = blockIdx.z;
    int hh = pp / PADW, ww = pp % PADW;
    char* dst = xsp + (size_t)n * NSTR + (size_t)g * GSTR + (size_t)pp * STRW;
    unsigned int wd[8];
    if (hh == 0 || hh == PADW - 1 || ww == 0 || ww == PADW - 1) {
#pragma unroll
        for (int m = 0; m < 8; ++m) wd[m] = 0u;
    } else {
        const float* xp = x + ((size_t)(n * CIN + g * 32)) * NPIX
                            + (size_t)(hh - 1) * HW + (ww - 1);
#pragma unroll
        for (int m = 0; m < 8; ++m) {
            unsigned int v = 0;
#pragma unroll
            for (int jj = 0; jj < 4; ++jj) {
                unsigned int b = (xp[(size_t)(m * 4 + jj) * NPIX] > 0.0f) ? 0x01u : 0xFFu;
                v |= b << (8 * jj);
            }
            wd[m] = v;
        }
    }
    ((i32x4*)dst)[0] = *(i32x4*)&wd[0];
    ((i32x4*)dst)[1] = *(i32x4*)&wd[4];
}

// ---------------------------------------------------------------------------
// Pack sign(W) to wsp[kidx][s][co][16] i8, kidx = g*9 + kh*3 + kw, s = k-half.
// ---------------------------------------------------------------------------
__global__ __launch_bounds__(256) void pack_w(const float* __restrict__ wt,
                                              char* __restrict__ wsp) {
    int b  = blockIdx.x;         // kidx
    int co = threadIdx.x;
    int g  = b / 9, r = b % 9;
    const float* wp = wt + ((size_t)co * CIN + g * 32) * 9 + r;
#pragma unroll
    for (int s = 0; s < 2; ++s) {
        unsigned int wd[4];
#pragma unroll
        for (int m = 0; m < 4; ++m) {
            unsigned int v = 0;
#pragma unroll
            for (int jj = 0; jj < 4; ++jj) {
                unsigned int bb = (wp[(size_t)(s * 16 + m * 4 + jj) * 9] > 0.0f) ? 0x01u : 0xFFu;
                v |= bb << (8 * jj);
            }
            wd[m] = v;
        }
        *(i32x4*)(wsp + ((size_t)(b * 2 + s) * COUT + co) * 16) = *(i32x4*)wd;
    }
}

// ---------------------------------------------------------------------------
__device__ inline void gload16(const void* g, void* l) {
    __builtin_amdgcn_global_load_lds(
        (const __attribute__((address_space(1))) unsigned int*)g,
        (__attribute__((address_space(3))) unsigned int*)l, 16, 0, 0);
}

// ---------------------------------------------------------------------------
// Implicit-GEMM XNOR conv, mfma_i32_32x32x32_i8. r5 geometry: block =
// 128co x 256pix, 4 waves, wave = 128co x 64pix (acc 4x2 x i32x16 = 128
// regs). BK=64 (2 kidx per phase, 36 phases): half the barriers of r4,
// 32 MFMA per 12 ds_read_b128 per wave-phase (was 16 per 5 -> LDS pipe
// was co-critical with matrix).
// LDS per buffer: A [kk2][s2][128row][16B]=8KB, B [kk2][s2][256row][16B]
// =16KB; k-major => lane-consecutive 16B slots, conflict-free (r4: 0).
// Frag maps (r4 verified, absmax=0): A row=l&31, k=(l>>5)*16+e;
// D col=l&31 (pixel), row(co)=(r&3)+8*(r>>2)+4*(l>>5).
// ---------------------------------------------------------------------------
__global__ __launch_bounds__(256, 2) void conv_mfma(const char* __restrict__ xsp,
                                                    const char* __restrict__ wsp,
                                                    const float* __restrict__ alpha,
                                                    float* __restrict__ out) {
    __shared__ char lA[2][8192];
    __shared__ char lB[2][16384];
    int tid   = threadIdx.x;
    int ptile = blockIdx.x;     // 392 pixel tiles (392*256 = 100352 exact)
    int mtile = blockIdx.y;     // 2 co tiles

    // A staging: slot d = w*256+tid -> kk=w, s=tid>>7, row=tid&127
    size_t aconst = (size_t)((tid >> 7) & 1) * 4096
                  + (size_t)(mtile * 128 + (tid & 127)) * 16;
    // B staging: slot d = w*256+tid -> kk=w>>1, s=w&1, row=tid (pixel)
    int pix = ptile * 256 + tid;
    int n = pix / NPIX, pq = pix % NPIX;
    int h = pq / HW, w = pq % HW;
    size_t boff = (size_t)n * NSTR + (size_t)h * ROWB + (size_t)w * STRW;

    i32x16 acc[4][2] = {};

    // prologue: stage phase 0 (kidx 0,1)
    {
#pragma unroll
        for (int wslot = 0; wslot < 2; ++wslot)
            gload16(wsp + (size_t)wslot * 8192 + aconst, &lA[0][wslot * 4096 + tid * 16]);
        // kidx 0 = (g0,kh0,kw0); kidx 1 = (g0,kh0,kw1)
#pragma unroll
        for (int wslot = 0; wslot < 4; ++wslot) {
            int kk = wslot >> 1, s = wslot & 1;
            gload16(xsp + boff + (size_t)kk * STRW + (size_t)s * 16,
                    &lB[0][wslot * 4096 + tid * 16]);
        }
    }
    __syncthreads();

    int l = tid & 63, wv = tid >> 6;
    int sA = (l >> 5) * 2048;           // A k-half select
    int sB = (l >> 5) * 4096;           // B k-half select
    int l31_16 = (l & 31) * 16;
    int bbase = wv * 1024 + l31_16;     // wave's pixel base within B tile

    for (int t = 0; t < NPH; ++t) {
        int buf = t & 1;
        if (t < NPH - 1) {
            int k0 = 2 * (t + 1);
#pragma unroll
            for (int wslot = 0; wslot < 2; ++wslot)
                gload16(wsp + (size_t)(k0 + wslot) * 8192 + aconst,
                        &lA[buf ^ 1][wslot * 4096 + tid * 16]);
#pragma unroll
            for (int wslot = 0; wslot < 4; ++wslot) {
                int kidx = k0 + (wslot >> 1), s = wslot & 1;
                int g = kidx / 9, r = kidx % 9, kh = r / 3, kw = r % 3;
                gload16(xsp + boff + (size_t)g * GSTR + (size_t)kh * ROWB
                            + (size_t)kw * STRW + (size_t)s * 16,
                        &lB[buf ^ 1][wslot * 4096 + tid * 16]);
            }
        }
#pragma unroll
        for (int kk = 0; kk < 2; ++kk) {
            i32x4 bf[2], af[4];
#pragma unroll
            for (int ni = 0; ni < 2; ++ni)
                bf[ni] = *(const i32x4*)&lB[buf][kk * 8192 + sB + bbase + ni * 512];
#pragma unroll
            for (int mi = 0; mi < 4; ++mi)
                af[mi] = *(const i32x4*)&lA[buf][kk * 4096 + sA + mi * 512 + l31_16];
#pragma unroll
            for (int mi = 0; mi < 4; ++mi)
#pragma unroll
                for (int ni = 0; ni < 2; ++ni)
                    acc[mi][ni] = __builtin_amdgcn_mfma_i32_32x32x32_i8(
                        af[mi], bf[ni], acc[mi][ni], 0, 0, 0);
        }
        __syncthreads();
    }

    // epilogue: D col = pixel (lane-contiguous), row = co
    int hi = l >> 5;
#pragma unroll
    for (int ni = 0; ni < 2; ++ni) {
        int pixo = ptile * 256 + wv * 64 + ni * 32 + (l & 31);
        int on = pixo / NPIX, opp = pixo % NPIX;
        float* ob = out + (size_t)on * COUT * NPIX + opp;
#pragma unroll
        for (int mi = 0; mi < 4; ++mi) {
#pragma unroll
            for (int r = 0; r < 16; ++r) {
                int co = mtile * 128 + mi * 32 + (r & 3) + 8 * (r >> 2) + 4 * hi;
                ob[(size_t)co * NPIX] = alpha[co] * (float)acc[mi][ni][r];
            }
        }
    }
}

// ---------------------------------------------------------------------------
extern "C" void kernel_launch(void* const* d_in, const int* in_sizes, int n_in,
                              void* d_out, int out_size, void* d_ws, size_t ws_size,
                              hipStream_t stream) {
    const float* x     = (const float*)d_in[0];
    const float* wt    = (const float*)d_in[1];
    const float* alpha = (const float*)d_in[2];
    float* out = (float*)d_out;

    char* ws  = (char*)d_ws;
    char* xsp = ws;                                   // 32*861184 = 27,557,888 B
    char* wsp = ws + (size_t)NB * NSTR;               // 72*8192   =    589,824 B

    pack_x<<<dim3(14, NB, 8), 256, 0, stream>>>(x, xsp);
    pack_w<<<dim3(NKID), 256, 0, stream>>>(wt, wsp);
    conv_mfma<<<dim3(392, 2), 256, 0, stream>>>(xsp, wsp, alpha, out);
}